// Round 6
// baseline (390.268 us; speedup 1.0000x reference)
//
#include <hip/hip_runtime.h>

#define B_   512
#define T_   365
#define DD_  5
#define DS_  27
#define H_   256
#define ROWS 2
#define NBLK (B_ / ROWS)      // 256 blocks = 1 per CU
#define NW   4
#define NTHR (NW * 64)        // 256 threads = 4 waves = 1 wave/SIMD

typedef _Float16 half8_t __attribute__((ext_vector_type(8)));
typedef float    f32x4   __attribute__((ext_vector_type(4)));

#define LOG2E_ 1.4426950408889634f

__device__ __forceinline__ float sigmoid_f(float x) {
    return __builtin_amdgcn_rcpf(1.0f + __builtin_amdgcn_exp2f(-x * LOG2E_));
}
__device__ __forceinline__ float tanh_f(float x) {
    return 1.0f - 2.0f * __builtin_amdgcn_rcpf(1.0f + __builtin_amdgcn_exp2f(2.0f * LOG2E_ * x));
}

__global__ __launch_bounds__(NTHR, 1)
void ealstm_kernel(const float* __restrict__ xdyn,   // [B,T,DD]
                   const float* __restrict__ xstat,  // [B,DS]
                   const float* __restrict__ Wi, const float* __restrict__ bi,
                   const float* __restrict__ Wf, const float* __restrict__ bf_,
                   const float* __restrict__ Wg, const float* __restrict__ bg,
                   const float* __restrict__ Wo, const float* __restrict__ bo,
                   const float* __restrict__ Wh, const float* __restrict__ bh,
                   float* __restrict__ out)
{
    const int tid = threadIdx.x;
    const int l   = tid & 63;
    const int w   = tid >> 6;
    const int b0  = blockIdx.x * ROWS;

    // h double-buffer: 16 rows (MFMA M) x 264 f16 (528B pitch)
    __shared__ __align__(16) _Float16 hbuf[2][16][264];
    __shared__ __align__(16) float xsh[ROWS][T_][8];   // stride-8 padded -> float4-able
    __shared__ float red[2][NW];

    // zero both h buffers (rows >= ROWS stay zero forever)
    {
        _Float16* hz = &hbuf[0][0][0];
        for (int i = tid; i < 2 * 16 * 264; i += NTHR) hz[i] = (_Float16)0.0f;
    }
    // preload x_dynamic (padded stride 8)
    for (int i = tid; i < ROWS * T_ * DD_; i += NTHR) {
        int r   = i / (T_ * DD_);
        int rem = i - r * (T_ * DD_);
        int tt  = rem / DD_;
        int d   = rem - tt * DD_;
        xsh[r][tt][d] = xdyn[(size_t)(b0 + r) * (T_ * DD_) + rem];
    }

    // ---- persistent B fragments: wave w owns cols [w*64, w*64+64) = 4 tiles,
    // both matrices. lane l holds B[k = ks*32 + 8*(l>>4) + i][col = tile + (l&15)]
    const int colW = w * 64;
    const int lg   = l >> 4;
    const int lm   = l & 15;
    half8_t Bf[2][4][8];          // 64 half8 = 256 VGPRs
    {
#pragma unroll
        for (int m = 0; m < 2; ++m) {
            const float* Ws = (m == 0) ? Wg : Wo;
#pragma unroll
            for (int tt = 0; tt < 4; ++tt) {
#pragma unroll
                for (int ks = 0; ks < 8; ++ks) {
                    int col = colW + tt * 16 + lm;
                    int k   = ks * 32 + 8 * lg;
                    const float* p = Ws + (size_t)(DD_ + k) * H_ + col;
                    half8_t v;
#pragma unroll
                    for (int i = 0; i < 8; ++i) v[i] = (_Float16)p[(size_t)i * H_];
                    Bf[m][tt][ks] = v;
                }
            }
        }
    }

    // ---- per-lane ownership: TWO elements.
    // elemA: row r_l=(l>>4)&1, col cA = colW + (l>>5)*16 + lm   (tiles 0,1)
    // elemB: same row, col cB = cA + 32                          (tiles 2,3)
    const int r_l  = (l >> 4) & 1;
    const int tsel = l >> 5;
    const int cA   = colW + tsel * 16 + lm;
    const int cB   = cA + 32;

    float WgxA[DD_], WoxA[DD_], WgxB[DD_], WoxB[DD_];
#pragma unroll
    for (int d = 0; d < DD_; ++d) {
        WgxA[d] = Wg[d * H_ + cA];
        WoxA[d] = Wo[d * H_ + cA];
        WgxB[d] = Wg[d * H_ + cB];
        WoxB[d] = Wo[d * H_ + cB];
    }
    const float bgA = bg[cA], boA = bo[cA];
    const float bgB = bg[cB], boB = bo[cB];

    float iGA, fGA, cstA = 0.0f, iGB, fGB, cstB = 0.0f;
    {
        float aiA = bi[cA], afA = bf_[cA], aiB = bi[cB], afB = bf_[cB];
        for (int d = 0; d < DS_; ++d) {
            float xv = xstat[(b0 + r_l) * DS_ + d];
            aiA += xv * Wi[d * H_ + cA];
            afA += xv * Wf[d * H_ + cA];
            aiB += xv * Wi[d * H_ + cB];
            afB += xv * Wf[d * H_ + cB];
        }
        iGA = sigmoid_f(aiA);  fGA = sigmoid_f(afA);
        iGB = sigmoid_f(aiB);  fGB = sigmoid_f(afB);
    }

    half8_t Af[8];
    {
        half8_t z;
#pragma unroll
        for (int i = 0; i < 8; ++i) z[i] = (_Float16)0.0f;
#pragma unroll
        for (int ks = 0; ks < 8; ++ks) Af[ks] = z;
    }
    const bool areal = (lm < ROWS);

    __syncthreads();

    for (int t = 0; t < T_; ++t) {
        const int cur = t & 1;
        const int nxt = cur ^ 1;

        // A fragments
        if (areal) {
#pragma unroll
            for (int ks = 0; ks < 8; ++ks)
                Af[ks] = *(const half8_t*)&hbuf[cur][lm][ks * 32 + 8 * lg];
        }

        // x-parts for both owned elements (hide under Af read latency)
        const float4 xv = *(const float4*)&xsh[r_l][t][0];
        const float  x4 = xsh[r_l][t][4];
        float xgA = bgA + xv.x*WgxA[0] + xv.y*WgxA[1] + xv.z*WgxA[2] + xv.w*WgxA[3] + x4*WgxA[4];
        float xoA = boA + xv.x*WoxA[0] + xv.y*WoxA[1] + xv.z*WoxA[2] + xv.w*WoxA[3] + x4*WoxA[4];
        float xgB = bgB + xv.x*WgxB[0] + xv.y*WgxB[1] + xv.z*WgxB[2] + xv.w*WgxB[3] + x4*WgxB[4];
        float xoB = boB + xv.x*WoxB[0] + xv.y*WoxB[1] + xv.z*WoxB[2] + xv.w*WoxB[3] + x4*WoxB[4];

        f32x4 aG0 = {0.f,0.f,0.f,0.f}, aG1 = {0.f,0.f,0.f,0.f};
        f32x4 aG2 = {0.f,0.f,0.f,0.f}, aG3 = {0.f,0.f,0.f,0.f};
        f32x4 aO0 = {0.f,0.f,0.f,0.f}, aO1 = {0.f,0.f,0.f,0.f};
        f32x4 aO2 = {0.f,0.f,0.f,0.f}, aO3 = {0.f,0.f,0.f,0.f};

        // ---- stage A burst: tiles 0,1 (32 MFMA) ----
#pragma unroll
        for (int ks = 0; ks < 8; ++ks) {
            aG0 = __builtin_amdgcn_mfma_f32_16x16x32_f16(Af[ks], Bf[0][0][ks], aG0, 0, 0, 0);
            aO0 = __builtin_amdgcn_mfma_f32_16x16x32_f16(Af[ks], Bf[1][0][ks], aO0, 0, 0, 0);
            aG1 = __builtin_amdgcn_mfma_f32_16x16x32_f16(Af[ks], Bf[0][1][ks], aG1, 0, 0, 0);
            aO1 = __builtin_amdgcn_mfma_f32_16x16x32_f16(Af[ks], Bf[1][1][ks], aO1, 0, 0, 0);
        }

        // stage A redistribute (depends only on burst A)
        float sg0a = __shfl(aG0[0], lm), sg1a = __shfl(aG0[1], lm);
        float sg0b = __shfl(aG1[0], lm), sg1b = __shfl(aG1[1], lm);
        float so0a = __shfl(aO0[0], lm), so1a = __shfl(aO0[1], lm);
        float so0b = __shfl(aO1[0], lm), so1b = __shfl(aO1[1], lm);

        // ---- stage B burst, first half: tiles 2,3 ks 0..3 ----
#pragma unroll
        for (int ks = 0; ks < 4; ++ks) {
            aG2 = __builtin_amdgcn_mfma_f32_16x16x32_f16(Af[ks], Bf[0][2][ks], aG2, 0, 0, 0);
            aO2 = __builtin_amdgcn_mfma_f32_16x16x32_f16(Af[ks], Bf[1][2][ks], aO2, 0, 0, 0);
            aG3 = __builtin_amdgcn_mfma_f32_16x16x32_f16(Af[ks], Bf[0][3][ks], aG3, 0, 0, 0);
            aO3 = __builtin_amdgcn_mfma_f32_16x16x32_f16(Af[ks], Bf[1][3][ks], aO3, 0, 0, 0);
        }

        // stage A epilogue (overlaps stage B MFMAs)
        {
            float pgA = (tsel ? (r_l ? sg1b : sg0b) : (r_l ? sg1a : sg0a)) + xgA;
            float poA = (tsel ? (r_l ? so1b : so0b) : (r_l ? so1a : so0a)) + xoA;
            float gA  = tanh_f(pgA);
            float oA  = sigmoid_f(poA);
            cstA = fGA * cstA + iGA * gA;
            float hA = oA * tanh_f(cstA);
            hbuf[nxt][r_l][cA] = (_Float16)hA;
        }

        // ---- stage B burst, second half: ks 4..7 ----
#pragma unroll
        for (int ks = 4; ks < 8; ++ks) {
            aG2 = __builtin_amdgcn_mfma_f32_16x16x32_f16(Af[ks], Bf[0][2][ks], aG2, 0, 0, 0);
            aO2 = __builtin_amdgcn_mfma_f32_16x16x32_f16(Af[ks], Bf[1][2][ks], aO2, 0, 0, 0);
            aG3 = __builtin_amdgcn_mfma_f32_16x16x32_f16(Af[ks], Bf[0][3][ks], aG3, 0, 0, 0);
            aO3 = __builtin_amdgcn_mfma_f32_16x16x32_f16(Af[ks], Bf[1][3][ks], aO3, 0, 0, 0);
        }

        // stage B redistribute + epilogue (exposed tail)
        {
            float tg0a = __shfl(aG2[0], lm), tg1a = __shfl(aG2[1], lm);
            float tg0b = __shfl(aG3[0], lm), tg1b = __shfl(aG3[1], lm);
            float to0a = __shfl(aO2[0], lm), to1a = __shfl(aO2[1], lm);
            float to0b = __shfl(aO3[0], lm), to1b = __shfl(aO3[1], lm);
            float pgB = (tsel ? (r_l ? tg1b : tg0b) : (r_l ? tg1a : tg0a)) + xgB;
            float poB = (tsel ? (r_l ? to1b : to0b) : (r_l ? to1a : to0a)) + xoB;
            float gB  = tanh_f(pgB);
            float oB  = sigmoid_f(poB);
            cstB = fGB * cstB + iGB * gB;
            float hB = oB * tanh_f(cstB);
            hbuf[nxt][r_l][cB] = (_Float16)hB;
        }
        __syncthreads();
    }

    // ---- output: out[b] = sum_c h[b][c] * Wh[c] + bh ----
    const int fin = T_ & 1;
    float v0 = (float)hbuf[fin][0][tid] * Wh[tid];
    float v1 = (float)hbuf[fin][1][tid] * Wh[tid];
#pragma unroll
    for (int off = 32; off > 0; off >>= 1) {
        v0 += __shfl_down(v0, off);
        v1 += __shfl_down(v1, off);
    }
    if (l == 0) { red[0][w] = v0; red[1][w] = v1; }
    __syncthreads();
    if (tid < ROWS) {
        out[b0 + tid] = red[tid][0] + red[tid][1] + red[tid][2] + red[tid][3] + bh[0];
    }
}

extern "C" void kernel_launch(void* const* d_in, const int* in_sizes, int n_in,
                              void* d_out, int out_size, void* d_ws, size_t ws_size,
                              hipStream_t stream) {
    (void)in_sizes; (void)n_in; (void)out_size; (void)d_ws; (void)ws_size;
    const float* xdyn  = (const float*)d_in[0];
    const float* xstat = (const float*)d_in[1];
    const float* Wi    = (const float*)d_in[2];
    const float* bi    = (const float*)d_in[3];
    const float* Wf    = (const float*)d_in[4];
    const float* bf    = (const float*)d_in[5];
    const float* Wg    = (const float*)d_in[6];
    const float* bg    = (const float*)d_in[7];
    const float* Wo    = (const float*)d_in[8];
    const float* bo    = (const float*)d_in[9];
    const float* Wh    = (const float*)d_in[10];
    const float* bh    = (const float*)d_in[11];
    float* out = (float*)d_out;

    hipLaunchKernelGGL(ealstm_kernel, dim3(NBLK), dim3(NTHR), 0, stream,
                       xdyn, xstat, Wi, bi, Wf, bf, Wg, bg, Wo, bo, Wh, bh, out);
}

// Round 7
// 299.813 us; speedup vs baseline: 1.3017x; 1.3017x over previous
//
#include <hip/hip_runtime.h>

#define B_   512
#define T_   365
#define DD_  5
#define DS_  27
#define H_   256
#define ROWS 2
#define NBLK (B_ / ROWS)      // 256 blocks = 1 per CU
#define NW   8
#define NTHR (NW * 64)        // 512 threads

typedef _Float16 half8_t __attribute__((ext_vector_type(8)));
typedef float    f32x4   __attribute__((ext_vector_type(4)));

#define LOG2E_ 1.4426950408889634f

__device__ __forceinline__ float sigmoid_f(float x) {
    return __builtin_amdgcn_rcpf(1.0f + __builtin_amdgcn_exp2f(-x * LOG2E_));
}
__device__ __forceinline__ float tanh_f(float x) {
    return 1.0f - 2.0f * __builtin_amdgcn_rcpf(1.0f + __builtin_amdgcn_exp2f(2.0f * LOG2E_ * x));
}

__global__ __launch_bounds__(NTHR, 2)
void ealstm_kernel(const float* __restrict__ xdyn,   // [B,T,DD]
                   const float* __restrict__ xstat,  // [B,DS]
                   const float* __restrict__ Wi, const float* __restrict__ bi,
                   const float* __restrict__ Wf, const float* __restrict__ bf_,
                   const float* __restrict__ Wg, const float* __restrict__ bg,
                   const float* __restrict__ Wo, const float* __restrict__ bo,
                   const float* __restrict__ Wh, const float* __restrict__ bh,
                   float* __restrict__ out)
{
    const int tid = threadIdx.x;
    const int l   = tid & 63;
    const int w   = tid >> 6;
    const int b0  = blockIdx.x * ROWS;

    // h double-buffer: just the 2 REAL rows (batch rows 0,1), 264-f16 pitch.
    // Batch row 0 feeds MFMA A-row 0; batch row 1 feeds A-row 4 (lanes l&15==4).
    // All other A-rows stay zero in registers -> C rows 0 and 4 are the real ones,
    // living in acc reg 0 of lane groups 0 and 1 (C row = 4*(lane>>4) + reg).
    __shared__ __align__(16) _Float16 hbuf[2][2][264];
    __shared__ __align__(16) float xsh[ROWS][T_][8];   // padded stride-8
    __shared__ float red[2][NW];

    // zero h buffers
    {
        _Float16* hz = &hbuf[0][0][0];
        for (int i = tid; i < 2 * 2 * 264; i += NTHR) hz[i] = (_Float16)0.0f;
    }
    // preload x_dynamic (padded)
    for (int i = tid; i < ROWS * T_ * DD_; i += NTHR) {
        int r   = i / (T_ * DD_);
        int rem = i - r * (T_ * DD_);
        int tt  = rem / DD_;
        int d   = rem - tt * DD_;
        xsh[r][tt][d] = xdyn[(size_t)(b0 + r) * (T_ * DD_) + rem];
    }

    // ---- persistent B fragments (fp16, MFMA 16x16x32 layout), wave w: cols [w*32, w*32+32)
    const int colW = w * 32;
    const int lg   = l >> 4;
    const int lm   = l & 15;
    half8_t Bf[2][2][8];      // 32 half8 = 128 regs (AGPR-eligible)
    {
#pragma unroll
        for (int m = 0; m < 2; ++m) {
            const float* Ws = (m == 0) ? Wg : Wo;
#pragma unroll
            for (int tt = 0; tt < 2; ++tt) {
#pragma unroll
                for (int ks = 0; ks < 8; ++ks) {
                    int col = colW + tt * 16 + lm;
                    int k   = ks * 32 + 8 * lg;
                    const float* p = Ws + (size_t)(DD_ + k) * H_ + col;
                    half8_t v;
#pragma unroll
                    for (int i = 0; i < 8; ++i) v[i] = (_Float16)p[(size_t)i * H_];
                    Bf[m][tt][ks] = v;
                }
            }
        }
    }

    // ---- per-lane ownership: lane l -> (row r_l, col c_l)
    // groups 0,1 (l<32): tile0 cols, rows 0,1  -> value is own acc reg 0 (tile0)
    // groups 2,3 (l>=32): tile1 cols, rows 0,1 -> pulled from lane l-32's tile1 acc reg 0
    const int r_l = (l >> 4) & 1;
    const int c_l = colW + (l >> 5) * 16 + lm;

    float Wgx[DD_], Wox[DD_];
#pragma unroll
    for (int d = 0; d < DD_; ++d) {
        Wgx[d] = Wg[d * H_ + c_l];
        Wox[d] = Wo[d * H_ + c_l];
    }
    const float bgv = bg[c_l], bov = bo[c_l];

    float iG, fG, cst = 0.0f;
    {
        float ai = bi[c_l], af = bf_[c_l];
        for (int d = 0; d < DS_; ++d) {
            float xv = xstat[(b0 + r_l) * DS_ + d];
            ai += xv * Wi[d * H_ + c_l];
            af += xv * Wf[d * H_ + c_l];
        }
        iG = sigmoid_f(ai);
        fG = sigmoid_f(af);
    }

    half8_t Af[8];
    {
        half8_t z;
#pragma unroll
        for (int i = 0; i < 8; ++i) z[i] = (_Float16)0.0f;
#pragma unroll
        for (int ks = 0; ks < 8; ++ks) Af[ks] = z;
    }
    const bool areal = (lm == 0) || (lm == 4);   // A-rows 0 and 4
    const int  arow  = lm >> 2;                  // 0 -> h row 0, 4 -> h row 1

    __syncthreads();

    for (int t = 0; t < T_; ++t) {
        const int cur = t & 1;
        const int nxt = cur ^ 1;

        // A fragments (2 lanes per 16-group; rest stay zero)
        if (areal) {
#pragma unroll
            for (int ks = 0; ks < 8; ++ks)
                Af[ks] = *(const half8_t*)&hbuf[cur][arow][ks * 32 + 8 * lg];
        }

        // per-lane x-part (h-independent, hides Af latency)
        const float4 xv = *(const float4*)&xsh[r_l][t][0];
        const float  x4 = xsh[r_l][t][4];
        float xg = bgv + xv.x*Wgx[0] + xv.y*Wgx[1] + xv.z*Wgx[2] + xv.w*Wgx[3] + x4*Wgx[4];
        float xo = bov + xv.x*Wox[0] + xv.y*Wox[1] + xv.z*Wox[2] + xv.w*Wox[3] + x4*Wox[4];

        f32x4 accG0 = {0.f,0.f,0.f,0.f}, accG1 = {0.f,0.f,0.f,0.f};
        f32x4 accO0 = {0.f,0.f,0.f,0.f}, accO1 = {0.f,0.f,0.f,0.f};
        __builtin_amdgcn_s_setprio(1);
#pragma unroll
        for (int ks = 0; ks < 8; ++ks) {
            accG0 = __builtin_amdgcn_mfma_f32_16x16x32_f16(Af[ks], Bf[0][0][ks], accG0, 0, 0, 0);
            accG1 = __builtin_amdgcn_mfma_f32_16x16x32_f16(Af[ks], Bf[0][1][ks], accG1, 0, 0, 0);
            accO0 = __builtin_amdgcn_mfma_f32_16x16x32_f16(Af[ks], Bf[1][0][ks], accO0, 0, 0, 0);
            accO1 = __builtin_amdgcn_mfma_f32_16x16x32_f16(Af[ks], Bf[1][1][ks], accO1, 0, 0, 0);
        }
        __builtin_amdgcn_s_setprio(0);

        // redistribute: lanes >=32 pull tile1 values from lane l-32; 1 shfl/gate
        float sG = __shfl(accG1[0], l & 31);
        float sO = __shfl(accO1[0], l & 31);
        float pg = ((l < 32) ? accG0[0] : sG) + xg;
        float po = ((l < 32) ? accO0[0] : sO) + xo;

        float g = tanh_f(pg);
        float o = sigmoid_f(po);
        cst = fG * cst + iG * g;
        float hv = o * tanh_f(cst);
        hbuf[nxt][r_l][c_l] = (_Float16)hv;

        __syncthreads();
    }

    // ---- output: out[b] = sum_c h[b][c] * Wh[c] + bh ----
    const int fin = T_ & 1;
    const int oc   = tid & 255;
    const int orow = tid >> 8;
    float v = (float)hbuf[fin][orow][oc] * Wh[oc];
#pragma unroll
    for (int off = 32; off > 0; off >>= 1)
        v += __shfl_down(v, off);
    if (l == 0) red[orow][w & 3] = v;
    __syncthreads();
    if (tid < ROWS) {
        out[b0 + tid] = red[tid][0] + red[tid][1] + red[tid][2] + red[tid][3] + bh[0];
    }
}

extern "C" void kernel_launch(void* const* d_in, const int* in_sizes, int n_in,
                              void* d_out, int out_size, void* d_ws, size_t ws_size,
                              hipStream_t stream) {
    (void)in_sizes; (void)n_in; (void)out_size; (void)d_ws; (void)ws_size;
    const float* xdyn  = (const float*)d_in[0];
    const float* xstat = (const float*)d_in[1];
    const float* Wi    = (const float*)d_in[2];
    const float* bi    = (const float*)d_in[3];
    const float* Wf    = (const float*)d_in[4];
    const float* bf    = (const float*)d_in[5];
    const float* Wg    = (const float*)d_in[6];
    const float* bg    = (const float*)d_in[7];
    const float* Wo    = (const float*)d_in[8];
    const float* bo    = (const float*)d_in[9];
    const float* Wh    = (const float*)d_in[10];
    const float* bh    = (const float*)d_in[11];
    float* out = (float*)d_out;

    hipLaunchKernelGGL(ealstm_kernel, dim3(NBLK), dim3(NTHR), 0, stream,
                       xdyn, xstat, Wi, bi, Wf, bf, Wg, bg, Wo, bo, Wh, bh, out);
}

// Round 8
// 289.105 us; speedup vs baseline: 1.3499x; 1.0370x over previous
//
#include <hip/hip_runtime.h>

#define B_   512
#define T_   365
#define DD_  5
#define DS_  27
#define H_   256
#define ROWS 2
#define NBLK (B_ / ROWS)      // 256 blocks = 1 per CU
#define NW   8
#define NTHR (NW * 64)        // 512 threads
#define HP   288              // h row pitch (f16): 576B = 144 dwords -> row1 at bank +16

typedef _Float16 half8_t __attribute__((ext_vector_type(8)));
typedef float    f32x4   __attribute__((ext_vector_type(4)));

#define LOG2E_ 1.4426950408889634f

__device__ __forceinline__ float sigmoid_f(float x) {
    return __builtin_amdgcn_rcpf(1.0f + __builtin_amdgcn_exp2f(-x * LOG2E_));
}
__device__ __forceinline__ float tanh_f(float x) {
    return 1.0f - 2.0f * __builtin_amdgcn_rcpf(1.0f + __builtin_amdgcn_exp2f(2.0f * LOG2E_ * x));
}

__global__ __launch_bounds__(NTHR, 2)
void ealstm_kernel(const float* __restrict__ xdyn,   // [B,T,DD]
                   const float* __restrict__ xstat,  // [B,DS]
                   const float* __restrict__ Wi, const float* __restrict__ bi,
                   const float* __restrict__ Wf, const float* __restrict__ bf_,
                   const float* __restrict__ Wg, const float* __restrict__ bg,
                   const float* __restrict__ Wo, const float* __restrict__ bo,
                   const float* __restrict__ Wh, const float* __restrict__ bh,
                   float* __restrict__ out)
{
    const int tid = threadIdx.x;
    const int l   = tid & 63;
    const int w   = tid >> 6;
    const int b0  = blockIdx.x * ROWS;

    // h double-buffer: 2 real rows, 288-f16 pitch (rows land in disjoint
    // 16-bank halves for both the 8-lane A-read and the 64-lane b16 write).
    // Batch row 0 -> MFMA A-row 0 (lanes lm==0); batch row 1 -> A-row 4
    // (lanes lm==4). C row = 4*(lane>>4)+reg, so acc reg 0 of lane groups
    // 0/1 holds batch rows 0/1 directly.
    __shared__ __align__(16) _Float16 hbuf[2][2][HP];
    __shared__ __align__(16) float xsh[ROWS][T_][8];   // padded stride-8
    __shared__ float red[2][NW];

    // zero h buffers
    {
        _Float16* hz = &hbuf[0][0][0];
        for (int i = tid; i < 2 * 2 * HP; i += NTHR) hz[i] = (_Float16)0.0f;
    }
    // preload x_dynamic (padded)
    for (int i = tid; i < ROWS * T_ * DD_; i += NTHR) {
        int r   = i / (T_ * DD_);
        int rem = i - r * (T_ * DD_);
        int tt  = rem / DD_;
        int d   = rem - tt * DD_;
        xsh[r][tt][d] = xdyn[(size_t)(b0 + r) * (T_ * DD_) + rem];
    }

    // ---- persistent B fragments (fp16, MFMA 16x16x32 layout), wave w: cols [w*32, w*32+32)
    const int colW = w * 32;
    const int lg   = l >> 4;
    const int lm   = l & 15;
    half8_t Bf[2][2][8];      // 32 half8 = 128 regs
    {
#pragma unroll
        for (int m = 0; m < 2; ++m) {
            const float* Ws = (m == 0) ? Wg : Wo;
#pragma unroll
            for (int tt = 0; tt < 2; ++tt) {
#pragma unroll
                for (int ks = 0; ks < 8; ++ks) {
                    int col = colW + tt * 16 + lm;
                    int k   = ks * 32 + 8 * lg;
                    const float* p = Ws + (size_t)(DD_ + k) * H_ + col;
                    half8_t v;
#pragma unroll
                    for (int i = 0; i < 8; ++i) v[i] = (_Float16)p[(size_t)i * H_];
                    Bf[m][tt][ks] = v;
                }
            }
        }
    }

    // ---- per-lane ownership: lane l -> (row r_l, col c_l)
    // l<32: tile0 cols, rows 0/1 -> own acc reg 0
    // l>=32: tile1 cols, rows 0/1 -> pulled from lane l-32's tile1 acc reg 0
    const int r_l = (l >> 4) & 1;
    const int c_l = colW + (l >> 5) * 16 + lm;

    float Wgx[DD_], Wox[DD_];
#pragma unroll
    for (int d = 0; d < DD_; ++d) {
        Wgx[d] = Wg[d * H_ + c_l];
        Wox[d] = Wo[d * H_ + c_l];
    }
    const float bgv = bg[c_l], bov = bo[c_l];

    float iG, fG, cst = 0.0f;
    {
        float ai = bi[c_l], af = bf_[c_l];
        for (int d = 0; d < DS_; ++d) {
            float xv = xstat[(b0 + r_l) * DS_ + d];
            ai += xv * Wi[d * H_ + c_l];
            af += xv * Wf[d * H_ + c_l];
        }
        iG = sigmoid_f(ai);
        fG = sigmoid_f(af);
    }

    half8_t Af[8];
    {
        half8_t z;
#pragma unroll
        for (int i = 0; i < 8; ++i) z[i] = (_Float16)0.0f;
#pragma unroll
        for (int ks = 0; ks < 8; ++ks) Af[ks] = z;
    }
    const bool areal = (lm == 0) || (lm == 4);   // A-rows 0 and 4
    const int  arow  = lm >> 2;                  // 0 -> h row 0, 4 -> h row 1

    __syncthreads();

    for (int t = 0; t < T_; ++t) {
        const int cur = t & 1;
        const int nxt = cur ^ 1;

        // A fragments (2 lanes per 16-group; rest stay zero)
        if (areal) {
#pragma unroll
            for (int ks = 0; ks < 8; ++ks)
                Af[ks] = *(const half8_t*)&hbuf[cur][arow][ks * 32 + 8 * lg];
        }

        // per-lane x-part (h-independent, hides Af latency)
        const float4 xv = *(const float4*)&xsh[r_l][t][0];
        const float  x4 = xsh[r_l][t][4];
        float xg = bgv + xv.x*Wgx[0] + xv.y*Wgx[1] + xv.z*Wgx[2] + xv.w*Wgx[3] + x4*Wgx[4];
        float xo = bov + xv.x*Wox[0] + xv.y*Wox[1] + xv.z*Wox[2] + xv.w*Wox[3] + x4*Wox[4];

        f32x4 accG0 = {0.f,0.f,0.f,0.f}, accG1 = {0.f,0.f,0.f,0.f};
        f32x4 accO0 = {0.f,0.f,0.f,0.f}, accO1 = {0.f,0.f,0.f,0.f};
        __builtin_amdgcn_s_setprio(1);
#pragma unroll
        for (int ks = 0; ks < 8; ++ks) {
            accG0 = __builtin_amdgcn_mfma_f32_16x16x32_f16(Af[ks], Bf[0][0][ks], accG0, 0, 0, 0);
            accG1 = __builtin_amdgcn_mfma_f32_16x16x32_f16(Af[ks], Bf[0][1][ks], accG1, 0, 0, 0);
            accO0 = __builtin_amdgcn_mfma_f32_16x16x32_f16(Af[ks], Bf[1][0][ks], accO0, 0, 0, 0);
            accO1 = __builtin_amdgcn_mfma_f32_16x16x32_f16(Af[ks], Bf[1][1][ks], accO1, 0, 0, 0);
        }
        __builtin_amdgcn_s_setprio(0);

        // redistribute: lanes >=32 pull tile1 values from lane l-32; 1 shfl/gate
        float sG = __shfl(accG1[0], l & 31);
        float sO = __shfl(accO1[0], l & 31);
        float pg = ((l < 32) ? accG0[0] : sG) + xg;
        float po = ((l < 32) ? accO0[0] : sO) + xo;

        float g = tanh_f(pg);
        float o = sigmoid_f(po);
        cst = fG * cst + iG * g;
        float hv = o * tanh_f(cst);
        hbuf[nxt][r_l][c_l] = (_Float16)hv;

        __syncthreads();
    }

    // ---- output: out[b] = sum_c h[b][c] * Wh[c] + bh ----
    const int fin  = T_ & 1;
    const int oc   = tid & 255;
    const int orow = tid >> 8;
    float v = (float)hbuf[fin][orow][oc] * Wh[oc];
#pragma unroll
    for (int off = 32; off > 0; off >>= 1)
        v += __shfl_down(v, off);
    if (l == 0) red[orow][w & 3] = v;
    __syncthreads();
    if (tid < ROWS) {
        out[b0 + tid] = red[tid][0] + red[tid][1] + red[tid][2] + red[tid][3] + bh[0];
    }
}

extern "C" void kernel_launch(void* const* d_in, const int* in_sizes, int n_in,
                              void* d_out, int out_size, void* d_ws, size_t ws_size,
                              hipStream_t stream) {
    (void)in_sizes; (void)n_in; (void)out_size; (void)d_ws; (void)ws_size;
    const float* xdyn  = (const float*)d_in[0];
    const float* xstat = (const float*)d_in[1];
    const float* Wi    = (const float*)d_in[2];
    const float* bi    = (const float*)d_in[3];
    const float* Wf    = (const float*)d_in[4];
    const float* bf    = (const float*)d_in[5];
    const float* Wg    = (const float*)d_in[6];
    const float* bg    = (const float*)d_in[7];
    const float* Wo    = (const float*)d_in[8];
    const float* bo    = (const float*)d_in[9];
    const float* Wh    = (const float*)d_in[10];
    const float* bh    = (const float*)d_in[11];
    float* out = (float*)d_out;

    hipLaunchKernelGGL(ealstm_kernel, dim3(NBLK), dim3(NTHR), 0, stream,
                       xdyn, xstat, Wi, bi, Wf, bf, Wg, bg, Wo, bo, Wh, bh, out);
}